// Round 1
// 611.864 us; speedup vs baseline: 1.0395x; 1.0395x over previous
//
#include <hip/hip_runtime.h>
#include <cstdint>

typedef unsigned short u16;
typedef unsigned int u32;

#define AS1 __attribute__((address_space(1)))
#define AS3 __attribute__((address_space(3)))

typedef _Float16 f16x8 __attribute__((ext_vector_type(8)));
typedef float f32x4 __attribute__((ext_vector_type(4)));

static constexpr int Bb = 2, Ss = 4096, Dd = 1024, Ff = 4096;
static constexpr int Mtok = Bb * Ss;          // 8192
static constexpr int NCH = 128;               // scan chunks per sequence
static constexpr int TCH = Ss / NCH;          // 32 steps per chunk
static constexpr int PW = 6144;               // fused projection width / pcat row stride

__device__ __forceinline__ float h2f(u16 u) {
    union { u16 u; _Float16 h; } w; w.u = u; return (float)w.h;
}
__device__ __forceinline__ u16 f2h(float f) {
    union { _Float16 h; u16 u; } w; w.h = (_Float16)f; return w.u;
}

// async global->LDS, 16 B per lane (m97 pattern; addrspacecast via C-cast)
__device__ __forceinline__ void gload_lds16(const u16* g, u16* l) {
    __builtin_amdgcn_global_load_lds((const AS1 u32*)g, (AS3 u32*)l, 16, 0, 0);
}

// ---------------- convert fp32 -> fp16, vectorized ----------------
__global__ __launch_bounds__(256) void cvt_f32_f16(const float* __restrict__ src,
                                                   u16* __restrict__ dst) {
    const long i = ((long)blockIdx.x * 256 + threadIdx.x) * 4;
    float4 f = *(const float4*)(src + i);
    ushort4 o;
    o.x = f2h(f.x); o.y = f2h(f.y); o.z = f2h(f.z); o.w = f2h(f.w);
    *(ushort4*)(dst + i) = o;
}

// ---------- transpose+convert: src fp32 [K,N] row-major -> dst fp16 [N,K] ----------
__global__ __launch_bounds__(1024) void transpose_f32_f16(const float* __restrict__ src,
                                                          u16* __restrict__ dst,
                                                          int K, int N) {
    __shared__ u16 t[32][33];
    const int tx = threadIdx.x, ty = threadIdx.y;
    const int n0 = blockIdx.x * 32, k0 = blockIdx.y * 32;
    t[ty][tx] = f2h(src[(long)(k0 + ty) * N + n0 + tx]);
    __syncthreads();
    dst[(long)(n0 + ty) * K + k0 + tx] = t[tx][ty];
}

// ------- GEMM: C[M,N] = A[M,K] @ B[K,N]; BT given [N,K] contiguous; A/C strided -------
// EPI: 0 = none, 1 = +bias, gelu(tanh), 2 = +bias   (bias fp32)
// (kept for the narrow GEMMs: Wo-proj and FFN2, where 256^2 tiles under-occupy)
template <int EPI>
__global__ __launch_bounds__(256, 2) void gemm_bt(const u16* __restrict__ A,
                                                  const u16* __restrict__ BT,
                                                  u16* __restrict__ C,
                                                  const float* __restrict__ bias,
                                                  int M, int N, int K,
                                                  int lda, int ldc) {
    __shared__ __align__(16) u16 sA[128 * 32];
    __shared__ __align__(16) u16 sB[128 * 32];
    const int tid = threadIdx.x;
    const int tm = blockIdx.y * 128;
    const int tn = blockIdx.x * 128;
    const int w = tid >> 6;
    const int lane = tid & 63;
    const int wm = (w >> 1) * 64;
    const int wn = (w & 1) * 64;
    const int q = lane >> 4;
    const int r16 = lane & 15;

    f32x4 acc[4][4];
#pragma unroll
    for (int i = 0; i < 4; i++)
#pragma unroll
        for (int j = 0; j < 4; j++) acc[i][j] = (f32x4){0.f, 0.f, 0.f, 0.f};

    const int s0 = tid, s1 = 256 + tid;
    const int row0 = s0 >> 2, kc0 = (s0 & 3) * 8;
    const int row1 = s1 >> 2, kc1 = (s1 & 3) * 8;
    const u16* Ar0 = A + (long)(tm + row0) * lda + kc0;
    const u16* Ar1 = A + (long)(tm + row1) * lda + kc1;
    const u16* Br0 = BT + (long)(tn + row0) * K + kc0;
    const u16* Br1 = BT + (long)(tn + row1) * K + kc1;

    const int kiters = K >> 5;
    for (int kt = 0; kt < kiters; ++kt) {
        const int ko = kt * 32;
        gload_lds16(Ar0 + ko, sA + s0 * 8);
        gload_lds16(Ar1 + ko, sA + s1 * 8);
        gload_lds16(Br0 + ko, sB + s0 * 8);
        gload_lds16(Br1 + ko, sB + s1 * 8);
        __syncthreads();
        f16x8 af[4], bfr[4];
#pragma unroll
        for (int mi = 0; mi < 4; mi++)
            af[mi] = *(const f16x8*)(sA + (wm + mi * 16 + r16) * 32 + q * 8);
#pragma unroll
        for (int ni = 0; ni < 4; ni++)
            bfr[ni] = *(const f16x8*)(sB + (wn + ni * 16 + r16) * 32 + q * 8);
#pragma unroll
        for (int mi = 0; mi < 4; mi++)
#pragma unroll
            for (int ni = 0; ni < 4; ni++)
                acc[mi][ni] = __builtin_amdgcn_mfma_f32_16x16x32_f16(
                    af[mi], bfr[ni], acc[mi][ni], 0, 0, 0);
        __syncthreads();
    }

#pragma unroll
    for (int mi = 0; mi < 4; mi++) {
#pragma unroll
        for (int ni = 0; ni < 4; ni++) {
            const int gcol = tn + wn + ni * 16 + r16;
            float bv = 0.f;
            if (EPI) bv = bias[gcol];
#pragma unroll
            for (int j = 0; j < 4; j++) {
                const int grow = tm + wm + mi * 16 + q * 4 + j;
                float v = acc[mi][ni][j];
                if (EPI) v += bv;
                if (EPI == 1) {
                    float t = tanhf(0.7978845608028654f * (v + 0.044715f * v * v * v));
                    v = 0.5f * v * (1.0f + t);
                }
                C[(long)grow * ldc + gcol] = f2h(v);
            }
        }
    }
}

// ===================== 256x256 8-phase GEMM (m201-style template) =====================
// BM=BN=256, BK=64, 512 threads = 8 waves (2M x 4N), per-wave output 128x64.
// LDS 128 KiB: 2 dbuf x (A[256][64] + B[256][64]) fp16, XOR-swizzled 16B chunks:
//   element (row,k) lives at chunk (k>>3) ^ (row&7)  -> conflict-free ds_read_b128.
// Staging: global_load_lds writes linearly, so the global SOURCE column is
// pre-swizzled per-thread (rule 21: linear dest + inverse-swz source + swz read).
// Schedule per K-tile (4 phases, reading buf cur, tiles clamped at the tail):
//   p0: vmcnt(4); barrier; read B(8)+A(mi0,1)(4); stage other.A h0 (tile it+1)
//   p1: read A(mi2,3); stage other.A h1 (tile it+1)
//   p2: read A(mi4,5); stage cur.B h0 (tile it+2)
//   p3: read A(mi6,7); stage cur.B h1 (tile it+2)
// each phase: [reads; stage; barrier; lgkmcnt(0); setprio(1); 16 MFMA; setprio(0); barrier]
// vmcnt(4) once per K-tile: 12 stage-instrs outstanding, oldest 8 = cur tile's A+B.
template <int EPI>
__global__ __launch_bounds__(512, 2) void gemm8p(const u16* __restrict__ A,
                                                 const u16* __restrict__ BT,
                                                 u16* __restrict__ C,
                                                 const float* __restrict__ bias,
                                                 int M, int N, int K,
                                                 int lda, int ldc) {
    extern __shared__ u16 lds[];  // [buf0: A 16384 | B 16384][buf1: A | B] u16
    const int tid = threadIdx.x;

    // XCD-aware bijective swizzle (grid % 8 == 0 for both call sites)
    const int ntn = N >> 8;
    int bid = blockIdx.x;
    {
        const int cpx = gridDim.x >> 3;
        bid = (bid & 7) * cpx + (bid >> 3);
    }
    const int tm = (bid / ntn) << 8;
    const int tn = (bid % ntn) << 8;

    // ---- staging addresses (pre-swizzled global source) ----
    const int srow = tid >> 3;                          // 0..63 within a 64-row round
    const int scol = ((tid & 7) ^ (srow & 7)) << 3;     // swizzled k-chunk * 8
    const u16* Abase = A + (long)(tm + srow) * lda + scol;
    const u16* Bbase = BT + (long)(tn + srow) * (long)K + scol;
    const long lda64 = (long)lda << 6;   // 64 rows of A
    const long ldb64 = (long)K << 6;     // 64 rows of B^T

    const int nt = K >> 6;

    auto stA = [&](u16* bufbase, int h, int kt) {
        u16* d = bufbase + h * 8192 + tid * 8;
        const u16* g = Abase + (long)(h * 128) * lda + (kt << 6);
        gload_lds16(g, d);
        gload_lds16(g + lda64, d + 4096);
    };
    auto stB = [&](u16* bufbase, int h, int kt) {
        u16* d = bufbase + 16384 + h * 8192 + tid * 8;
        const u16* g = Bbase + (long)(h * 128) * (long)K + (kt << 6);
        gload_lds16(g, d);
        gload_lds16(g + ldb64, d + 4096);
    };

    // ---- fragment read addresses (swizzled) ----
    const int wid = tid >> 6, lane = tid & 63;
    const int r16 = lane & 15, q = lane >> 4;
    const int wm = (wid >> 2) * 128;     // 0 / 128
    const int wn = (wid & 3) * 64;       // 0 / 64 / 128 / 192
    const int r7 = r16 & 7;
    const int cx0 = (q ^ r7) << 3;        // k-half 0 chunk offset (u16)
    const int cx1 = ((4 | q) ^ r7) << 3;  // k-half 1
    const int aoff = (wm + r16) * 64;
    const int boff = 16384 + (wn + r16) * 64;

    f32x4 acc[8][4];
#pragma unroll
    for (int i = 0; i < 8; i++)
#pragma unroll
        for (int j = 0; j < 4; j++) acc[i][j] = (f32x4){0.f, 0.f, 0.f, 0.f};

    // ---- prologue: buf0 <- tile0 (A,B), buf1.B <- tile1 ----
    {
        const int t1 = nt > 1 ? 1 : 0;
        stA(lds, 0, 0);
        stA(lds, 1, 0);
        stB(lds, 0, 0);
        stB(lds, 1, 0);
        stB(lds + 32768, 0, t1);
        stB(lds + 32768, 1, t1);
    }

    for (int it = 0; it < nt; ++it) {
        u16* sb = lds + ((it & 1) << 15);          // current buffer
        u16* so = lds + (((it & 1) ^ 1) << 15);    // other buffer
        const int tA = (it + 1 < nt) ? it + 1 : nt - 1;
        const int tB = (it + 2 < nt) ? it + 2 : nt - 1;

        asm volatile("s_waitcnt vmcnt(4)" ::: "memory");
        __builtin_amdgcn_s_barrier();

        f16x8 vb[4][2];
#pragma unroll
        for (int ni = 0; ni < 4; ni++) {
            vb[ni][0] = *(const f16x8*)(sb + boff + ni * 1024 + cx0);
            vb[ni][1] = *(const f16x8*)(sb + boff + ni * 1024 + cx1);
        }

#pragma unroll
        for (int p = 0; p < 4; ++p) {
            f16x8 pa[2][2];
#pragma unroll
            for (int m2 = 0; m2 < 2; m2++) {
                pa[m2][0] = *(const f16x8*)(sb + aoff + (2 * p + m2) * 1024 + cx0);
                pa[m2][1] = *(const f16x8*)(sb + aoff + (2 * p + m2) * 1024 + cx1);
            }
            if (p == 0)      stA(so, 0, tA);
            else if (p == 1) stA(so, 1, tA);
            else if (p == 2) stB(sb, 0, tB);
            else             stB(sb, 1, tB);
            __builtin_amdgcn_s_barrier();
            asm volatile("s_waitcnt lgkmcnt(0)" ::: "memory");
            __builtin_amdgcn_s_setprio(1);
#pragma unroll
            for (int m2 = 0; m2 < 2; m2++)
#pragma unroll
                for (int ni = 0; ni < 4; ni++) {
                    acc[2 * p + m2][ni] = __builtin_amdgcn_mfma_f32_16x16x32_f16(
                        pa[m2][0], vb[ni][0], acc[2 * p + m2][ni], 0, 0, 0);
                    acc[2 * p + m2][ni] = __builtin_amdgcn_mfma_f32_16x16x32_f16(
                        pa[m2][1], vb[ni][1], acc[2 * p + m2][ni], 0, 0, 0);
                }
            __builtin_amdgcn_s_setprio(0);
            __builtin_amdgcn_s_barrier();
        }
    }

    // drain stray tail prefetches before LDS is released
    asm volatile("s_waitcnt vmcnt(0)" ::: "memory");

#pragma unroll
    for (int mi = 0; mi < 8; mi++) {
#pragma unroll
        for (int ni = 0; ni < 4; ni++) {
            const int gcol = tn + wn + ni * 16 + r16;
            float bv = 0.f;
            if (EPI) bv = bias[gcol];
#pragma unroll
            for (int j = 0; j < 4; j++) {
                const int grow = tm + wm + mi * 16 + q * 4 + j;
                float v = acc[mi][ni][j];
                if (EPI) v += bv;
                if (EPI == 1) {
                    float t = tanhf(0.7978845608028654f * (v + 0.044715f * v * v * v));
                    v = 0.5f * v * (1.0f + t);
                }
                C[(long)grow * ldc + gcol] = f2h(v);
            }
        }
    }
}

// ---------------- a_c transform helper ----------------
__device__ __forceinline__ void a_transform(float ar, float ai, float& cr, float& ci) {
    float m = sqrtf(ar * ar + ai * ai);
    float sg = 1.f / (1.f + __expf(-m));
    float sc = sg / fmaxf(m, 1e-30f);
    cr = ar * sc;
    ci = ai * sc;
}

// pcat column offsets: Q=0, K=1024, V=2048, AR=3072, AI=4096, G=5120; row stride PW.
// ---------------- scan phase 1: per-chunk reduce ----------------
__global__ __launch_bounds__(1024) void scan1(const u16* __restrict__ pcat,
                                              float4* __restrict__ sum4) {
    const int b = blockIdx.y, c = blockIdx.x, d = threadIdx.x;
    float Arp = 1.f, Aip = 0.f, Xr = 0.f, Xi = 0.f;
    const long rowbase = (long)b * Ss + (long)c * TCH;
#pragma unroll 4
    for (int s = 0; s < TCH; ++s) {
        const long ro = (rowbase + s) * PW;
        float ar = h2f(pcat[ro + 3072 + d]);
        float ai = h2f(pcat[ro + 4096 + d]);
        float kk = h2f(pcat[ro + 1024 + d]);
        float vv = h2f(pcat[ro + 2048 + d]);
        float cr, ci;
        a_transform(ar, ai, cr, ci);
        float kv = kk * vv;
        float nXr = cr * Xr - ci * Xi + kv;
        float nXi = cr * Xi + ci * Xr;
        Xr = nXr; Xi = nXi;
        float nAr = cr * Arp - ci * Aip;
        float nAi = cr * Aip + ci * Arp;
        Arp = nAr; Aip = nAi;
    }
    sum4[((long)b * NCH + c) * 1024 + d] = make_float4(Arp, Aip, Xr, Xi);
}

// ---------------- scan phase 2: sequential carry across chunks ----------------
__global__ __launch_bounds__(256) void scan2(const float4* __restrict__ sum4,
                                             float2* __restrict__ carry) {
    const int idx = blockIdx.x * 256 + threadIdx.x;  // 0..2047
    const int b = idx >> 10, d = idx & 1023;
    float hr = 0.f, hi = 0.f;
    for (int cb = 0; cb < NCH / 8; ++cb) {
        float4 t[8];
#pragma unroll
        for (int j = 0; j < 8; j++)
            t[j] = sum4[((long)b * NCH + cb * 8 + j) * 1024 + d];
#pragma unroll
        for (int j = 0; j < 8; j++) {
            carry[((long)b * NCH + cb * 8 + j) * 1024 + d] = make_float2(hr, hi);
            float nr = t[j].x * hr - t[j].y * hi + t[j].z;
            float ni = t[j].x * hi + t[j].y * hr + t[j].w;
            hr = nr; hi = ni;
        }
    }
}

// -------- scan phase 3: re-scan with carry, fused silu/q gating; y over Q in-place --------
__global__ __launch_bounds__(1024) void scan3(u16* pcat,
                                              const float2* __restrict__ carry) {
    const int b = blockIdx.y, c = blockIdx.x, d = threadIdx.x;
    float2 h0 = carry[((long)b * NCH + c) * 1024 + d];
    float hr = h0.x, hi = h0.y;
    const long rowbase = (long)b * Ss + (long)c * TCH;
#pragma unroll 4
    for (int s = 0; s < TCH; ++s) {
        const long ro = (rowbase + s) * PW;
        float ar = h2f(pcat[ro + 3072 + d]);
        float ai = h2f(pcat[ro + 4096 + d]);
        float kk = h2f(pcat[ro + 1024 + d]);
        float vv = h2f(pcat[ro + 2048 + d]);
        float cr, ci;
        a_transform(ar, ai, cr, ci);
        float kv = kk * vv;
        float nhr = cr * hr - ci * hi + kv;
        float nhi = cr * hi + ci * hr;
        hr = nhr; hi = nhi;
        float gg = h2f(pcat[ro + 5120 + d]);
        float si = gg / (1.f + __expf(-gg));
        float yv = h2f(pcat[ro + d]) * hr * si;
        pcat[ro + d] = f2h(yv);
    }
}

// ---------------- layernorm: out = LN(a + res) * scale + bias ----------------
// a: fp16 (stride sa). RESF32: res fp32 (stride sres). OUTF32: out fp32 (stride sout).
template <int RESF32, int OUTF32>
__global__ __launch_bounds__(256) void ln_kernel(const u16* __restrict__ a, int sa,
                                                 const void* __restrict__ bres, int sres,
                                                 const float* __restrict__ scale,
                                                 const float* __restrict__ bias,
                                                 void* __restrict__ out, int sout) {
    const int row = blockIdx.x;
    const int tid = threadIdx.x;
    const long abase = (long)row * sa;
    const long rbase = (long)row * sres;
    const long obase = (long)row * sout;
    float v[4];
#pragma unroll
    for (int j = 0; j < 4; j++) {
        int d = tid * 4 + j;
        float rb = RESF32 ? ((const float*)bres)[rbase + d]
                          : h2f(((const u16*)bres)[rbase + d]);
        v[j] = h2f(a[abase + d]) + rb;
    }
    float s = v[0] + v[1] + v[2] + v[3];
    float s2 = v[0] * v[0] + v[1] * v[1] + v[2] * v[2] + v[3] * v[3];
#pragma unroll
    for (int off = 32; off; off >>= 1) {
        s += __shfl_down(s, off);
        s2 += __shfl_down(s2, off);
    }
    __shared__ float red[8];
    const int w = tid >> 6, lane = tid & 63;
    if (lane == 0) { red[w] = s; red[4 + w] = s2; }
    __syncthreads();
    if (tid == 0) {
        float ts = red[0] + red[1] + red[2] + red[3];
        float ts2 = red[4] + red[5] + red[6] + red[7];
        float mu = ts * (1.f / 1024.f);
        float var = ts2 * (1.f / 1024.f) - mu * mu;
        red[0] = mu;
        red[1] = rsqrtf(var + 1e-6f);
    }
    __syncthreads();
    const float mu = red[0], rs = red[1];
#pragma unroll
    for (int j = 0; j < 4; j++) {
        int d = tid * 4 + j;
        float y = (v[j] - mu) * rs * scale[d] + bias[d];
        if (OUTF32) ((float*)out)[obase + d] = y;
        else        ((u16*)out)[obase + d] = f2h(y);
    }
}

extern "C" void kernel_launch(void* const* d_in, const int* in_sizes, int n_in,
                              void* d_out, int out_size, void* d_ws, size_t ws_size,
                              hipStream_t stream) {
    const float* x    = (const float*)d_in[0];
    const float* Wq   = (const float*)d_in[1];
    const float* Wk   = (const float*)d_in[2];
    const float* Wv   = (const float*)d_in[3];
    const float* Wa   = (const float*)d_in[4];
    const float* Wg   = (const float*)d_in[5];
    const float* Wo   = (const float*)d_in[6];
    const float* ln1s = (const float*)d_in[7];
    const float* ln1b = (const float*)d_in[8];
    const float* W1   = (const float*)d_in[9];
    const float* b1   = (const float*)d_in[10];
    const float* W2   = (const float*)d_in[11];
    const float* b2   = (const float*)d_in[12];
    const float* ln2s = (const float*)d_in[13];
    const float* ln2b = (const float*)d_in[14];

    // ---- workspace layout (u16 elements), 142 MiB total ----
    u16* ws    = (u16*)d_ws;
    u16* xb    = ws;                        // 8M   x as fp16
    u16* WTcat = xb + (8u << 20);           // 6M   [6144,1024] fused proj weights^T
    u16* WTo   = WTcat + (6u << 20);        // 1M
    u16* WT1   = WTo + (1u << 20);          // 4M
    u16* WT2   = WT1 + (4u << 20);          // 4M
    u16* pcat  = WT2 + (4u << 20);          // 48M  [8192,6144] everything lives here
    // total = 71M u16 = 142 MiB

    // scan scratch overlays WTcat (dead after the fused projection GEMM)
    float4* sum4  = (float4*)WTcat;               // 4 MiB
    float2* carry = (float2*)(WTcat + (2u << 20)); // 2 MiB @ +4 MiB

    // allow 128 KiB dynamic LDS for the 8-phase GEMMs (once; host-side, capture-safe)
    static bool attr_done = false;
    if (!attr_done) {
        hipFuncSetAttribute(reinterpret_cast<const void*>(&gemm8p<0>),
                            hipFuncAttributeMaxDynamicSharedMemorySize, 131072);
        hipFuncSetAttribute(reinterpret_cast<const void*>(&gemm8p<1>),
                            hipFuncAttributeMaxDynamicSharedMemorySize, 131072);
        attr_done = true;
    }

    // pcat column slices (row stride PW=6144):
    //   Q=+0  K=+1024  V=+2048  AR=+3072  AI=+4096  G=+5120
    // liveness ladder: scan3 writes y over Q; Wo-GEMM Q->K(o1); LN1 K->Q(yln);
    // FFN1 Q->cols[2048,6144)(hmat); FFN2 hmat->K(o2); LN2 (K,Q)->d_out.

    // x -> fp16
    cvt_f32_f16<<<dim3(8192), dim3(256), 0, stream>>>(x, xb);

    const dim3 tb(32, 32);
    transpose_f32_f16<<<dim3(32, 32), tb, 0, stream>>>(Wq, WTcat, 1024, 1024);
    transpose_f32_f16<<<dim3(32, 32), tb, 0, stream>>>(Wk, WTcat + (1u << 20), 1024, 1024);
    transpose_f32_f16<<<dim3(32, 32), tb, 0, stream>>>(Wv, WTcat + (2u << 20), 1024, 1024);
    transpose_f32_f16<<<dim3(64, 32), tb, 0, stream>>>(Wa, WTcat + (3u << 20), 1024, 2048);
    transpose_f32_f16<<<dim3(32, 32), tb, 0, stream>>>(Wg, WTcat + (5u << 20), 1024, 1024);
    transpose_f32_f16<<<dim3(32, 32), tb, 0, stream>>>(Wo, WTo, 1024, 1024);
    transpose_f32_f16<<<dim3(128, 32), tb, 0, stream>>>(W1, WT1, 1024, 4096);
    transpose_f32_f16<<<dim3(32, 128), tb, 0, stream>>>(W2, WT2, 4096, 1024);

    const dim3 gblk(256);
    // fused q|k|v|a|g projection: [8192,1024] @ [1024,6144] -> pcat   (8-phase 256^2)
    gemm8p<0><<<dim3(768), dim3(512), 131072, stream>>>(xb, WTcat, pcat, nullptr,
                                                        Mtok, PW, 1024, 1024, PW);
    // gate-loop scan
    scan1<<<dim3(NCH, Bb), 1024, 0, stream>>>(pcat, sum4);
    scan2<<<dim3(8), 256, 0, stream>>>(sum4, carry);
    scan3<<<dim3(NCH, Bb), 1024, 0, stream>>>(pcat, carry);
    // output proj: y(Q slice) @ Wo -> o1(K slice)   (narrow: keep 128^2)
    gemm_bt<0><<<dim3(8, 64), gblk, 0, stream>>>(pcat, WTo, pcat + 1024, nullptr,
                                                 Mtok, 1024, 1024, PW, PW);
    // LN1: o1 + x -> yln(Q slice)
    ln_kernel<1, 0><<<dim3(Mtok), gblk, 0, stream>>>(pcat + 1024, PW, x, 1024,
                                                     ln1s, ln1b, pcat, PW);
    // FFN1: yln @ W1 + b1, gelu -> hmat(cols 2048..6144)   (8-phase 256^2)
    gemm8p<1><<<dim3(512), dim3(512), 131072, stream>>>(pcat, WT1, pcat + 2048, b1,
                                                        Mtok, Ff, 1024, PW, PW);
    // FFN2: hmat @ W2 + b2 -> o2(K slice)   (narrow: keep 128^2)
    gemm_bt<2><<<dim3(8, 64), gblk, 0, stream>>>(pcat + 2048, WT2, pcat + 1024, b2,
                                                 Mtok, 1024, Ff, PW, PW);
    // LN2: o2 + yln -> fp32 d_out
    ln_kernel<0, 1><<<dim3(Mtok), gblk, 0, stream>>>(pcat + 1024, PW, pcat, PW,
                                                     ln2s, ln2b, d_out, 1024);
}

// Round 2
// 565.584 us; speedup vs baseline: 1.1246x; 1.0818x over previous
//
#include <hip/hip_runtime.h>
#include <cstdint>

typedef unsigned short u16;
typedef unsigned int u32;

#define AS1 __attribute__((address_space(1)))
#define AS3 __attribute__((address_space(3)))

typedef _Float16 f16x8 __attribute__((ext_vector_type(8)));
typedef float f32x4 __attribute__((ext_vector_type(4)));

static constexpr int Bb = 2, Ss = 4096, Dd = 1024, Ff = 4096;
static constexpr int Mtok = Bb * Ss;          // 8192
static constexpr int NCH = 128;               // scan chunks per sequence
static constexpr int TCH = Ss / NCH;          // 32 steps per chunk
static constexpr int PW = 6144;               // fused projection width / pcat row stride

__device__ __forceinline__ float h2f(u16 u) {
    union { u16 u; _Float16 h; } w; w.u = u; return (float)w.h;
}
__device__ __forceinline__ u16 f2h(float f) {
    union { _Float16 h; u16 u; } w; w.h = (_Float16)f; return w.u;
}

// async global->LDS, 16 B per lane (m97 pattern; addrspacecast via C-cast)
__device__ __forceinline__ void gload_lds16(const u16* g, u16* l) {
    __builtin_amdgcn_global_load_lds((const AS1 u32*)g, (AS3 u32*)l, 16, 0, 0);
}

// ---------------- convert fp32 -> fp16, vectorized ----------------
__global__ __launch_bounds__(256) void cvt_f32_f16(const float* __restrict__ src,
                                                   u16* __restrict__ dst) {
    const long i = ((long)blockIdx.x * 256 + threadIdx.x) * 4;
    float4 f = *(const float4*)(src + i);
    ushort4 o;
    o.x = f2h(f.x); o.y = f2h(f.y); o.z = f2h(f.z); o.w = f2h(f.w);
    *(ushort4*)(dst + i) = o;
}

// ---------- transpose+convert: src fp32 [K,N] row-major -> dst fp16 [N,K] ----------
__global__ __launch_bounds__(1024) void transpose_f32_f16(const float* __restrict__ src,
                                                          u16* __restrict__ dst,
                                                          int K, int N) {
    __shared__ u16 t[32][33];
    const int tx = threadIdx.x, ty = threadIdx.y;
    const int n0 = blockIdx.x * 32, k0 = blockIdx.y * 32;
    t[ty][tx] = f2h(src[(long)(k0 + ty) * N + n0 + tx]);
    __syncthreads();
    dst[(long)(n0 + ty) * K + k0 + tx] = t[tx][ty];
}

// ===================== 256x256 8-phase GEMM (m201-style template) =====================
// BM=BN=256, BK=64, 512 threads = 8 waves (2M x 4N), per-wave output 128x64.
// LDS 128 KiB: 2 dbuf x (A[256][64] + B[256][64]) fp16, XOR-swizzled 16B chunks:
//   element (row,k) lives at chunk (k>>3) ^ (row&7)  -> conflict-free ds_read_b128.
// global_load_lds writes linearly -> pre-swizzle the global SOURCE column (rule 21).
// Per K-tile (4 phases): p0 stages other.A h0(it+1), p1 other.A h1(it+1),
// p2 cur.B h0(it+2), p3 cur.B h1(it+2); vmcnt(4) once per K-tile at iter top
// (in-flight: [B(it):4, A(it):4, B(it+1):4] -> drain oldest 8).
template <int EPI>
__global__ __launch_bounds__(512, 2) void gemm8p(const u16* __restrict__ A,
                                                 const u16* __restrict__ BT,
                                                 u16* __restrict__ C,
                                                 const float* __restrict__ bias,
                                                 int M, int N, int K,
                                                 int lda, int ldc) {
    extern __shared__ u16 lds[];  // [buf0: A 16384 | B 16384][buf1: A | B] u16
    const int tid = threadIdx.x;

    // XCD-aware bijective swizzle (grid % 8 == 0 for all call sites)
    const int ntn = N >> 8;
    int bid = blockIdx.x;
    {
        const int cpx = gridDim.x >> 3;
        bid = (bid & 7) * cpx + (bid >> 3);
    }
    const int tm = (bid / ntn) << 8;
    const int tn = (bid % ntn) << 8;

    // ---- staging addresses (pre-swizzled global source) ----
    const int srow = tid >> 3;                          // 0..63 within a 64-row round
    const int scol = ((tid & 7) ^ (srow & 7)) << 3;     // swizzled k-chunk * 8
    const u16* Abase = A + (long)(tm + srow) * lda + scol;
    const u16* Bbase = BT + (long)(tn + srow) * (long)K + scol;
    const long lda64 = (long)lda << 6;   // 64 rows of A
    const long ldb64 = (long)K << 6;     // 64 rows of B^T

    const int nt = K >> 6;

    auto stA = [&](u16* bufbase, int h, int kt) {
        u16* d = bufbase + h * 8192 + tid * 8;
        const u16* g = Abase + (long)(h * 128) * lda + (kt << 6);
        gload_lds16(g, d);
        gload_lds16(g + lda64, d + 4096);
    };
    auto stB = [&](u16* bufbase, int h, int kt) {
        u16* d = bufbase + 16384 + h * 8192 + tid * 8;
        const u16* g = Bbase + (long)(h * 128) * (long)K + (kt << 6);
        gload_lds16(g, d);
        gload_lds16(g + ldb64, d + 4096);
    };

    // ---- fragment read addresses (swizzled) ----
    const int wid = tid >> 6, lane = tid & 63;
    const int r16 = lane & 15, q = lane >> 4;
    const int wm = (wid >> 2) * 128;     // 0 / 128
    const int wn = (wid & 3) * 64;       // 0 / 64 / 128 / 192
    const int r7 = r16 & 7;
    const int cx0 = (q ^ r7) << 3;        // k-half 0 chunk offset (u16)
    const int cx1 = ((4 | q) ^ r7) << 3;  // k-half 1
    const int aoff = (wm + r16) * 64;
    const int boff = 16384 + (wn + r16) * 64;

    f32x4 acc[8][4];
#pragma unroll
    for (int i = 0; i < 8; i++)
#pragma unroll
        for (int j = 0; j < 4; j++) acc[i][j] = (f32x4){0.f, 0.f, 0.f, 0.f};

    // ---- prologue: buf0 <- tile0 (A,B), buf1.B <- tile1 ----
    {
        const int t1 = nt > 1 ? 1 : 0;
        stA(lds, 0, 0);
        stA(lds, 1, 0);
        stB(lds, 0, 0);
        stB(lds, 1, 0);
        stB(lds + 32768, 0, t1);
        stB(lds + 32768, 1, t1);
    }

    for (int it = 0; it < nt; ++it) {
        u16* sb = lds + ((it & 1) << 15);          // current buffer
        u16* so = lds + (((it & 1) ^ 1) << 15);    // other buffer
        const int tA = (it + 1 < nt) ? it + 1 : nt - 1;
        const int tB = (it + 2 < nt) ? it + 2 : nt - 1;

        asm volatile("s_waitcnt vmcnt(4)" ::: "memory");
        __builtin_amdgcn_s_barrier();

        f16x8 vb[4][2];
#pragma unroll
        for (int ni = 0; ni < 4; ni++) {
            vb[ni][0] = *(const f16x8*)(sb + boff + ni * 1024 + cx0);
            vb[ni][1] = *(const f16x8*)(sb + boff + ni * 1024 + cx1);
        }

#pragma unroll
        for (int p = 0; p < 4; ++p) {
            f16x8 pa[2][2];
#pragma unroll
            for (int m2 = 0; m2 < 2; m2++) {
                pa[m2][0] = *(const f16x8*)(sb + aoff + (2 * p + m2) * 1024 + cx0);
                pa[m2][1] = *(const f16x8*)(sb + aoff + (2 * p + m2) * 1024 + cx1);
            }
            if (p == 0)      stA(so, 0, tA);
            else if (p == 1) stA(so, 1, tA);
            else if (p == 2) stB(sb, 0, tB);
            else             stB(sb, 1, tB);
            __builtin_amdgcn_s_barrier();
            asm volatile("s_waitcnt lgkmcnt(0)" ::: "memory");
            __builtin_amdgcn_s_setprio(1);
#pragma unroll
            for (int m2 = 0; m2 < 2; m2++)
#pragma unroll
                for (int ni = 0; ni < 4; ni++) {
                    acc[2 * p + m2][ni] = __builtin_amdgcn_mfma_f32_16x16x32_f16(
                        pa[m2][0], vb[ni][0], acc[2 * p + m2][ni], 0, 0, 0);
                    acc[2 * p + m2][ni] = __builtin_amdgcn_mfma_f32_16x16x32_f16(
                        pa[m2][1], vb[ni][1], acc[2 * p + m2][ni], 0, 0, 0);
                }
            __builtin_amdgcn_s_setprio(0);
            __builtin_amdgcn_s_barrier();
        }
    }

    // drain stray tail prefetches before LDS is released
    asm volatile("s_waitcnt vmcnt(0)" ::: "memory");

#pragma unroll
    for (int mi = 0; mi < 8; mi++) {
#pragma unroll
        for (int ni = 0; ni < 4; ni++) {
            const int gcol = tn + wn + ni * 16 + r16;
            float bv = 0.f;
            if (EPI) bv = bias[gcol];
#pragma unroll
            for (int j = 0; j < 4; j++) {
                const int grow = tm + wm + mi * 16 + q * 4 + j;
                float v = acc[mi][ni][j];
                if (EPI) v += bv;
                if (EPI == 1) {
                    float t = tanhf(0.7978845608028654f * (v + 0.044715f * v * v * v));
                    v = 0.5f * v * (1.0f + t);
                }
                C[(long)grow * ldc + gcol] = f2h(v);
            }
        }
    }
}

// ================== 256x128 8-phase GEMM variant (narrow-N: Wo, FFN2) ==================
// BM=256, BN=128, BK=64, 512 threads = 8 waves (4M x 2N), per-wave output 64x64
// (acc 64 VGPR). Grid = (M/256)*(N/128) = 256 blocks -> exactly one generation.
// LDS 96 KiB: 2 dbuf x (A[256][64]=32KB + B[128][64]=16KB); same XOR-chunk swizzle.
// 2 phases/K-tile x 16 MFMA. Loads/K-tile: A 4, B 2.
//   p0: read vb(8)+pa(mi0,1)(4); stage other.A h0 (it+1)
//   p1: read pa(mi2,3)(4);       stage other.A h1 (it+1) + cur.B (it+2)
// vmcnt(2) once per K-tile: in-flight at iter top = [B(it):2, A(it):4, B(it+1):2],
// drain the oldest 6.
template <int EPI>
__global__ __launch_bounds__(512, 2) void gemm8p_n128(const u16* __restrict__ A,
                                                      const u16* __restrict__ BT,
                                                      u16* __restrict__ C,
                                                      const float* __restrict__ bias,
                                                      int M, int N, int K,
                                                      int lda, int ldc) {
    extern __shared__ u16 lds[];  // buf: A 16384 | B 8192 u16; buf stride 24576
    const int tid = threadIdx.x;

    const int ntn = N >> 7;
    int bid = blockIdx.x;
    {
        const int cpx = gridDim.x >> 3;
        bid = (bid & 7) * cpx + (bid >> 3);
    }
    const int tm = (bid / ntn) << 8;
    const int tn = (bid % ntn) << 7;

    const int srow = tid >> 3;
    const int scol = ((tid & 7) ^ (srow & 7)) << 3;
    const u16* Abase = A + (long)(tm + srow) * lda + scol;
    const u16* Bbase = BT + (long)(tn + srow) * (long)K + scol;
    const long lda64 = (long)lda << 6;
    const long ldb64 = (long)K << 6;

    const int nt = K >> 6;

    auto stA = [&](u16* bufbase, int h, int kt) {
        u16* d = bufbase + h * 8192 + tid * 8;
        const u16* g = Abase + (long)(h * 128) * lda + (kt << 6);
        gload_lds16(g, d);
        gload_lds16(g + lda64, d + 4096);
    };
    auto stB = [&](u16* bufbase, int kt) {
        u16* d = bufbase + 16384 + tid * 8;
        const u16* g = Bbase + (kt << 6);
        gload_lds16(g, d);
        gload_lds16(g + ldb64, d + 4096);
    };

    const int wid = tid >> 6, lane = tid & 63;
    const int r16 = lane & 15, q = lane >> 4;
    const int wm = (wid >> 1) * 64;      // 0 / 64 / 128 / 192
    const int wn = (wid & 1) * 64;       // 0 / 64
    const int r7 = r16 & 7;
    const int cx0 = (q ^ r7) << 3;
    const int cx1 = ((4 | q) ^ r7) << 3;
    const int aoff = (wm + r16) * 64;
    const int boff = 16384 + (wn + r16) * 64;

    f32x4 acc[4][4];
#pragma unroll
    for (int i = 0; i < 4; i++)
#pragma unroll
        for (int j = 0; j < 4; j++) acc[i][j] = (f32x4){0.f, 0.f, 0.f, 0.f};

    // prologue: buf0 <- tile0 (A,B); buf1.B <- tile1
    {
        const int t1 = nt > 1 ? 1 : 0;
        stA(lds, 0, 0);
        stA(lds, 1, 0);
        stB(lds, 0);
        stB(lds + 24576, t1);
    }

    for (int it = 0; it < nt; ++it) {
        u16* sb = lds + (it & 1) * 24576;
        u16* so = lds + ((it & 1) ^ 1) * 24576;
        const int tA = (it + 1 < nt) ? it + 1 : nt - 1;
        const int tB = (it + 2 < nt) ? it + 2 : nt - 1;

        asm volatile("s_waitcnt vmcnt(2)" ::: "memory");
        __builtin_amdgcn_s_barrier();

        f16x8 vb[4][2];
#pragma unroll
        for (int ni = 0; ni < 4; ni++) {
            vb[ni][0] = *(const f16x8*)(sb + boff + ni * 1024 + cx0);
            vb[ni][1] = *(const f16x8*)(sb + boff + ni * 1024 + cx1);
        }

#pragma unroll
        for (int p = 0; p < 2; ++p) {
            f16x8 pa[2][2];
#pragma unroll
            for (int m2 = 0; m2 < 2; m2++) {
                pa[m2][0] = *(const f16x8*)(sb + aoff + (2 * p + m2) * 1024 + cx0);
                pa[m2][1] = *(const f16x8*)(sb + aoff + (2 * p + m2) * 1024 + cx1);
            }
            if (p == 0) {
                stA(so, 0, tA);
            } else {
                stA(so, 1, tA);
                stB(sb, tB);
            }
            __builtin_amdgcn_s_barrier();
            asm volatile("s_waitcnt lgkmcnt(0)" ::: "memory");
            __builtin_amdgcn_s_setprio(1);
#pragma unroll
            for (int m2 = 0; m2 < 2; m2++)
#pragma unroll
                for (int ni = 0; ni < 4; ni++) {
                    acc[2 * p + m2][ni] = __builtin_amdgcn_mfma_f32_16x16x32_f16(
                        pa[m2][0], vb[ni][0], acc[2 * p + m2][ni], 0, 0, 0);
                    acc[2 * p + m2][ni] = __builtin_amdgcn_mfma_f32_16x16x32_f16(
                        pa[m2][1], vb[ni][1], acc[2 * p + m2][ni], 0, 0, 0);
                }
            __builtin_amdgcn_s_setprio(0);
            __builtin_amdgcn_s_barrier();
        }
    }

    asm volatile("s_waitcnt vmcnt(0)" ::: "memory");

#pragma unroll
    for (int mi = 0; mi < 4; mi++) {
#pragma unroll
        for (int ni = 0; ni < 4; ni++) {
            const int gcol = tn + wn + ni * 16 + r16;
            float bv = 0.f;
            if (EPI) bv = bias[gcol];
#pragma unroll
            for (int j = 0; j < 4; j++) {
                const int grow = tm + wm + mi * 16 + q * 4 + j;
                float v = acc[mi][ni][j];
                if (EPI) v += bv;
                if (EPI == 1) {
                    float t = tanhf(0.7978845608028654f * (v + 0.044715f * v * v * v));
                    v = 0.5f * v * (1.0f + t);
                }
                C[(long)grow * ldc + gcol] = f2h(v);
            }
        }
    }
}

// ---------------- a_c transform helper ----------------
__device__ __forceinline__ void a_transform(float ar, float ai, float& cr, float& ci) {
    float m = sqrtf(ar * ar + ai * ai);
    float sg = 1.f / (1.f + __expf(-m));
    float sc = sg / fmaxf(m, 1e-30f);
    cr = ar * sc;
    ci = ai * sc;
}

// pcat column offsets: Q=0, K=1024, V=2048, AR=3072, AI=4096, G=5120; row stride PW.
// ---------------- scan phase 1: per-chunk reduce ----------------
__global__ __launch_bounds__(1024) void scan1(const u16* __restrict__ pcat,
                                              float4* __restrict__ sum4) {
    const int b = blockIdx.y, c = blockIdx.x, d = threadIdx.x;
    float Arp = 1.f, Aip = 0.f, Xr = 0.f, Xi = 0.f;
    const long rowbase = (long)b * Ss + (long)c * TCH;
#pragma unroll 4
    for (int s = 0; s < TCH; ++s) {
        const long ro = (rowbase + s) * PW;
        float ar = h2f(pcat[ro + 3072 + d]);
        float ai = h2f(pcat[ro + 4096 + d]);
        float kk = h2f(pcat[ro + 1024 + d]);
        float vv = h2f(pcat[ro + 2048 + d]);
        float cr, ci;
        a_transform(ar, ai, cr, ci);
        float kv = kk * vv;
        float nXr = cr * Xr - ci * Xi + kv;
        float nXi = cr * Xi + ci * Xr;
        Xr = nXr; Xi = nXi;
        float nAr = cr * Arp - ci * Aip;
        float nAi = cr * Aip + ci * Arp;
        Arp = nAr; Aip = nAi;
    }
    sum4[((long)b * NCH + c) * 1024 + d] = make_float4(Arp, Aip, Xr, Xi);
}

// ---------------- scan phase 2: sequential carry across chunks ----------------
__global__ __launch_bounds__(256) void scan2(const float4* __restrict__ sum4,
                                             float2* __restrict__ carry) {
    const int idx = blockIdx.x * 256 + threadIdx.x;  // 0..2047
    const int b = idx >> 10, d = idx & 1023;
    float hr = 0.f, hi = 0.f;
    for (int cb = 0; cb < NCH / 8; ++cb) {
        float4 t[8];
#pragma unroll
        for (int j = 0; j < 8; j++)
            t[j] = sum4[((long)b * NCH + cb * 8 + j) * 1024 + d];
#pragma unroll
        for (int j = 0; j < 8; j++) {
            carry[((long)b * NCH + cb * 8 + j) * 1024 + d] = make_float2(hr, hi);
            float nr = t[j].x * hr - t[j].y * hi + t[j].z;
            float ni = t[j].x * hi + t[j].y * hr + t[j].w;
            hr = nr; hi = ni;
        }
    }
}

// -------- scan phase 3: re-scan with carry, fused silu/q gating; y over Q in-place --------
__global__ __launch_bounds__(1024) void scan3(u16* pcat,
                                              const float2* __restrict__ carry) {
    const int b = blockIdx.y, c = blockIdx.x, d = threadIdx.x;
    float2 h0 = carry[((long)b * NCH + c) * 1024 + d];
    float hr = h0.x, hi = h0.y;
    const long rowbase = (long)b * Ss + (long)c * TCH;
#pragma unroll 4
    for (int s = 0; s < TCH; ++s) {
        const long ro = (rowbase + s) * PW;
        float ar = h2f(pcat[ro + 3072 + d]);
        float ai = h2f(pcat[ro + 4096 + d]);
        float kk = h2f(pcat[ro + 1024 + d]);
        float vv = h2f(pcat[ro + 2048 + d]);
        float cr, ci;
        a_transform(ar, ai, cr, ci);
        float kv = kk * vv;
        float nhr = cr * hr - ci * hi + kv;
        float nhi = cr * hi + ci * hr;
        hr = nhr; hi = nhi;
        float gg = h2f(pcat[ro + 5120 + d]);
        float si = gg / (1.f + __expf(-gg));
        float yv = h2f(pcat[ro + d]) * hr * si;
        pcat[ro + d] = f2h(yv);
    }
}

// ---------------- layernorm: out = LN(a + res) * scale + bias ----------------
// a: fp16 (stride sa). RESF32: res fp32 (stride sres). OUTF32: out fp32 (stride sout).
template <int RESF32, int OUTF32>
__global__ __launch_bounds__(256) void ln_kernel(const u16* __restrict__ a, int sa,
                                                 const void* __restrict__ bres, int sres,
                                                 const float* __restrict__ scale,
                                                 const float* __restrict__ bias,
                                                 void* __restrict__ out, int sout) {
    const int row = blockIdx.x;
    const int tid = threadIdx.x;
    const long abase = (long)row * sa;
    const long rbase = (long)row * sres;
    const long obase = (long)row * sout;
    float v[4];
#pragma unroll
    for (int j = 0; j < 4; j++) {
        int d = tid * 4 + j;
        float rb = RESF32 ? ((const float*)bres)[rbase + d]
                          : h2f(((const u16*)bres)[rbase + d]);
        v[j] = h2f(a[abase + d]) + rb;
    }
    float s = v[0] + v[1] + v[2] + v[3];
    float s2 = v[0] * v[0] + v[1] * v[1] + v[2] * v[2] + v[3] * v[3];
#pragma unroll
    for (int off = 32; off; off >>= 1) {
        s += __shfl_down(s, off);
        s2 += __shfl_down(s2, off);
    }
    __shared__ float red[8];
    const int w = tid >> 6, lane = tid & 63;
    if (lane == 0) { red[w] = s; red[4 + w] = s2; }
    __syncthreads();
    if (tid == 0) {
        float ts = red[0] + red[1] + red[2] + red[3];
        float ts2 = red[4] + red[5] + red[6] + red[7];
        float mu = ts * (1.f / 1024.f);
        float var = ts2 * (1.f / 1024.f) - mu * mu;
        red[0] = mu;
        red[1] = rsqrtf(var + 1e-6f);
    }
    __syncthreads();
    const float mu = red[0], rs = red[1];
#pragma unroll
    for (int j = 0; j < 4; j++) {
        int d = tid * 4 + j;
        float y = (v[j] - mu) * rs * scale[d] + bias[d];
        if (OUTF32) ((float*)out)[obase + d] = y;
        else        ((u16*)out)[obase + d] = f2h(y);
    }
}

extern "C" void kernel_launch(void* const* d_in, const int* in_sizes, int n_in,
                              void* d_out, int out_size, void* d_ws, size_t ws_size,
                              hipStream_t stream) {
    const float* x    = (const float*)d_in[0];
    const float* Wq   = (const float*)d_in[1];
    const float* Wk   = (const float*)d_in[2];
    const float* Wv   = (const float*)d_in[3];
    const float* Wa   = (const float*)d_in[4];
    const float* Wg   = (const float*)d_in[5];
    const float* Wo   = (const float*)d_in[6];
    const float* ln1s = (const float*)d_in[7];
    const float* ln1b = (const float*)d_in[8];
    const float* W1   = (const float*)d_in[9];
    const float* b1   = (const float*)d_in[10];
    const float* W2   = (const float*)d_in[11];
    const float* b2   = (const float*)d_in[12];
    const float* ln2s = (const float*)d_in[13];
    const float* ln2b = (const float*)d_in[14];

    // ---- workspace layout (u16 elements), 142 MiB total ----
    u16* ws    = (u16*)d_ws;
    u16* xb    = ws;                        // 8M   x as fp16
    u16* WTcat = xb + (8u << 20);           // 6M   [6144,1024] fused proj weights^T
    u16* WTo   = WTcat + (6u << 20);        // 1M
    u16* WT1   = WTo + (1u << 20);          // 4M
    u16* WT2   = WT1 + (4u << 20);          // 4M
    u16* pcat  = WT2 + (4u << 20);          // 48M  [8192,6144] everything lives here
    // total = 71M u16 = 142 MiB

    // scan scratch overlays WTcat (dead after the fused projection GEMM)
    float4* sum4  = (float4*)WTcat;               // 4 MiB
    float2* carry = (float2*)(WTcat + (2u << 20)); // 2 MiB @ +4 MiB

    // allow big dynamic LDS for the 8-phase GEMMs (once; host-side, capture-safe)
    static bool attr_done = false;
    if (!attr_done) {
        hipFuncSetAttribute(reinterpret_cast<const void*>(&gemm8p<0>),
                            hipFuncAttributeMaxDynamicSharedMemorySize, 131072);
        hipFuncSetAttribute(reinterpret_cast<const void*>(&gemm8p<1>),
                            hipFuncAttributeMaxDynamicSharedMemorySize, 131072);
        hipFuncSetAttribute(reinterpret_cast<const void*>(&gemm8p_n128<0>),
                            hipFuncAttributeMaxDynamicSharedMemorySize, 98304);
        hipFuncSetAttribute(reinterpret_cast<const void*>(&gemm8p_n128<2>),
                            hipFuncAttributeMaxDynamicSharedMemorySize, 98304);
        attr_done = true;
    }

    // pcat column slices (row stride PW=6144):
    //   Q=+0  K=+1024  V=+2048  AR=+3072  AI=+4096  G=+5120
    // liveness ladder: scan3 writes y over Q; Wo-GEMM Q->K(o1); LN1 K->Q(yln);
    // FFN1 Q->cols[2048,6144)(hmat); FFN2 hmat->K(o2); LN2 (K,Q)->d_out.

    // x -> fp16
    cvt_f32_f16<<<dim3(8192), dim3(256), 0, stream>>>(x, xb);

    const dim3 tb(32, 32);
    transpose_f32_f16<<<dim3(32, 32), tb, 0, stream>>>(Wq, WTcat, 1024, 1024);
    transpose_f32_f16<<<dim3(32, 32), tb, 0, stream>>>(Wk, WTcat + (1u << 20), 1024, 1024);
    transpose_f32_f16<<<dim3(32, 32), tb, 0, stream>>>(Wv, WTcat + (2u << 20), 1024, 1024);
    transpose_f32_f16<<<dim3(64, 32), tb, 0, stream>>>(Wa, WTcat + (3u << 20), 1024, 2048);
    transpose_f32_f16<<<dim3(32, 32), tb, 0, stream>>>(Wg, WTcat + (5u << 20), 1024, 1024);
    transpose_f32_f16<<<dim3(32, 32), tb, 0, stream>>>(Wo, WTo, 1024, 1024);
    transpose_f32_f16<<<dim3(128, 32), tb, 0, stream>>>(W1, WT1, 1024, 4096);
    transpose_f32_f16<<<dim3(32, 128), tb, 0, stream>>>(W2, WT2, 4096, 1024);

    // fused q|k|v|a|g projection: [8192,1024] @ [1024,6144] -> pcat   (8-phase 256^2)
    gemm8p<0><<<dim3(768), dim3(512), 131072, stream>>>(xb, WTcat, pcat, nullptr,
                                                        Mtok, PW, 1024, 1024, PW);
    // gate-loop scan
    scan1<<<dim3(NCH, Bb), 1024, 0, stream>>>(pcat, sum4);
    scan2<<<dim3(8), 256, 0, stream>>>(sum4, carry);
    scan3<<<dim3(NCH, Bb), 1024, 0, stream>>>(pcat, carry);
    // output proj: y(Q slice) @ Wo -> o1(K slice)   (256x128 8-phase, 256 blocks)
    gemm8p_n128<0><<<dim3(256), dim3(512), 98304, stream>>>(pcat, WTo, pcat + 1024,
                                                            nullptr,
                                                            Mtok, 1024, 1024, PW, PW);
    // LN1: o1 + x -> yln(Q slice)
    ln_kernel<1, 0><<<dim3(Mtok), dim3(256), 0, stream>>>(pcat + 1024, PW, x, 1024,
                                                          ln1s, ln1b, pcat, PW);
    // FFN1: yln @ W1 + b1, gelu -> hmat(cols 2048..6144)   (8-phase 256^2)
    gemm8p<1><<<dim3(512), dim3(512), 131072, stream>>>(pcat, WT1, pcat + 2048, b1,
                                                        Mtok, Ff, 1024, PW, PW);
    // FFN2: hmat @ W2 + b2 -> o2(K slice)   (256x128 8-phase, 256 blocks, 64 K-tiles)
    gemm8p_n128<2><<<dim3(256), dim3(512), 98304, stream>>>(pcat + 2048, WT2,
                                                            pcat + 1024, b2,
                                                            Mtok, 1024, Ff, PW, PW);
    // LN2: o2 + yln -> fp32 d_out
    ln_kernel<0, 1><<<dim3(Mtok), dim3(256), 0, stream>>>(pcat + 1024, PW, pcat, PW,
                                                          ln2s, ln2b, d_out, 1024);
}

// Round 3
// 528.134 us; speedup vs baseline: 1.2043x; 1.0709x over previous
//
#include <hip/hip_runtime.h>
#include <cstdint>

typedef unsigned short u16;
typedef unsigned int u32;

#define AS1 __attribute__((address_space(1)))
#define AS3 __attribute__((address_space(3)))

typedef _Float16 f16x8 __attribute__((ext_vector_type(8)));
typedef float f32x4 __attribute__((ext_vector_type(4)));

static constexpr int Bb = 2, Ss = 4096, Dd = 1024, Ff = 4096;
static constexpr int Mtok = Bb * Ss;          // 8192
static constexpr int NCH = 128;               // scan chunks per sequence
static constexpr int TCH = Ss / NCH;          // 32 steps per chunk
static constexpr int PW = 6144;               // fused projection width / pcat row stride

__device__ __forceinline__ float h2f(u16 u) {
    union { u16 u; _Float16 h; } w; w.u = u; return (float)w.h;
}
__device__ __forceinline__ u16 f2h(float f) {
    union { _Float16 h; u16 u; } w; w.h = (_Float16)f; return w.u;
}

// async global->LDS, 16 B per lane (m97 pattern; addrspacecast via C-cast)
__device__ __forceinline__ void gload_lds16(const u16* g, u16* l) {
    __builtin_amdgcn_global_load_lds((const AS1 u32*)g, (AS3 u32*)l, 16, 0, 0);
}

// ============ fused prep: x->fp16 + all 8 weight transposes, ONE launch ============
// blocks [0,8192): cvt x (1024 f32/block)
// then 32x32 transpose tiles: Wq 1024, Wk 1024, Wv 1024, Wa 2048, Wg 1024,
// Wo 1024, W1 4096, W2 4096  (total grid 23552)
__global__ __launch_bounds__(256) void prep_fused(
    const float* __restrict__ x, u16* __restrict__ xb,
    const float* __restrict__ Wq, const float* __restrict__ Wk,
    const float* __restrict__ Wv, const float* __restrict__ Wa,
    const float* __restrict__ Wg, const float* __restrict__ Wo,
    const float* __restrict__ W1, const float* __restrict__ W2,
    u16* __restrict__ WTcat, u16* __restrict__ WTo,
    u16* __restrict__ WT1, u16* __restrict__ WT2) {
    __shared__ u16 t[32][33];
    const int tid = threadIdx.x;
    const int idx = blockIdx.x;
    if (idx < 8192) {
        const long i = ((long)idx * 256 + tid) * 4;
        float4 f = *(const float4*)(x + i);
        ushort4 o;
        o.x = f2h(f.x); o.y = f2h(f.y); o.z = f2h(f.z); o.w = f2h(f.w);
        *(ushort4*)(xb + i) = o;
        return;
    }
    const float* src; u16* dst; int K, N, ti;
    if (idx < 9216)       { src = Wq; dst = WTcat;             K = 1024; N = 1024; ti = idx - 8192; }
    else if (idx < 10240) { src = Wk; dst = WTcat + (1u << 20); K = 1024; N = 1024; ti = idx - 9216; }
    else if (idx < 11264) { src = Wv; dst = WTcat + (2u << 20); K = 1024; N = 1024; ti = idx - 10240; }
    else if (idx < 13312) { src = Wa; dst = WTcat + (3u << 20); K = 1024; N = 2048; ti = idx - 11264; }
    else if (idx < 14336) { src = Wg; dst = WTcat + (5u << 20); K = 1024; N = 1024; ti = idx - 13312; }
    else if (idx < 15360) { src = Wo; dst = WTo;               K = 1024; N = 1024; ti = idx - 14336; }
    else if (idx < 19456) { src = W1; dst = WT1;               K = 1024; N = 4096; ti = idx - 15360; }
    else                  { src = W2; dst = WT2;               K = 4096; N = 1024; ti = idx - 19456; }
    const int tiles_x = N >> 5;
    const int bx = ti % tiles_x, by = ti / tiles_x;
    const int n0 = bx << 5, k0 = by << 5;
    const int tx = tid & 31, ty = tid >> 5;   // ty 0..7
#pragma unroll
    for (int r = 0; r < 4; r++) {
        const int row = ty + r * 8;
        t[row][tx] = f2h(src[(long)(k0 + row) * N + n0 + tx]);
    }
    __syncthreads();
#pragma unroll
    for (int r = 0; r < 4; r++) {
        const int row = ty + r * 8;
        dst[(long)(n0 + row) * K + k0 + tx] = t[tx][row];
    }
}

// ===================== 256x256 8-phase GEMM, PERSISTENT (m201-style) =====================
// BM=BN=256, BK=64, 512 threads = 8 waves (2M x 4N), per-wave output 128x64.
// LDS 128 KiB: 2 dbuf x (A[256][64] + B[256][64]) fp16, XOR-swizzled 16B chunks:
//   element (row,k) lives at chunk (k>>3) ^ (row&7)  -> conflict-free ds_read_b128.
// global_load_lds writes linearly -> pre-swizzle the global SOURCE column (rule 21).
// PERSISTENT: each block owns tpb = total_tiles/gridDim.x output tiles; the tail
// staging of tile t redirects to tile t+1's kt0/kt1 (nt even => buffer parity is
// continuous across the seam), so the pipeline never drains between tiles.
// Steady in-flight at iter top: [B(g):4, A(g):4, B(g+1):4] -> vmcnt(4).
template <int EPI>
__global__ __launch_bounds__(512, 2) void gemm8p(const u16* __restrict__ A,
                                                 const u16* __restrict__ BT,
                                                 u16* __restrict__ C,
                                                 const float* __restrict__ bias,
                                                 int M, int N, int K,
                                                 int lda, int ldc) {
    extern __shared__ u16 lds[];  // [buf0: A 16384 | B 16384][buf1: A | B] u16
    const int tid = threadIdx.x;

    const int ntn = N >> 8;
    const int total = (M >> 8) * ntn;     // output tiles (multiple of 8 and of grid)
    const int tpb = total / (int)gridDim.x;
    const int cpx = total >> 3;           // XCD-bijective swizzle chunk

    // ---- staging thread mapping (pre-swizzled global source) ----
    const int srow = tid >> 3;                          // 0..63 within a 64-row round
    const int scol = ((tid & 7) ^ (srow & 7)) << 3;     // swizzled k-chunk * 8
    const long lda64 = (long)lda << 6;   // 64 rows of A
    const long ldb64 = (long)K << 6;     // 64 rows of B^T

    const int nt = K >> 6;

    auto bases_for = [&](int t, int& tm, int& tn, const u16*& Ab, const u16*& Bb) {
        if (t > tpb - 1) t = tpb - 1;
        const int ti = (int)blockIdx.x + t * (int)gridDim.x;
        const int b = (ti & 7) * cpx + (ti >> 3);
        tm = (b / ntn) << 8;
        tn = (b % ntn) << 8;
        Ab = A + (long)(tm + srow) * lda + scol;
        Bb = BT + (long)(tn + srow) * (long)K + scol;
    };

    auto stA = [&](u16* bufbase, int h, const u16* Ab, int kt) {
        u16* d = bufbase + h * 8192 + tid * 8;
        const u16* g = Ab + (long)(h * 128) * lda + (kt << 6);
        gload_lds16(g, d);
        gload_lds16(g + lda64, d + 4096);
    };
    auto stB = [&](u16* bufbase, int h, const u16* Bb, int kt) {
        u16* d = bufbase + 16384 + h * 8192 + tid * 8;
        const u16* g = Bb + (long)(h * 128) * (long)K + (kt << 6);
        gload_lds16(g, d);
        gload_lds16(g + ldb64, d + 4096);
    };

    // ---- fragment read addresses (swizzled) ----
    const int wid = tid >> 6, lane = tid & 63;
    const int r16 = lane & 15, q = lane >> 4;
    const int wm = (wid >> 2) * 128;     // 0 / 128
    const int wn = (wid & 3) * 64;       // 0 / 64 / 128 / 192
    const int r7 = r16 & 7;
    const int cx0 = (q ^ r7) << 3;        // k-half 0 chunk offset (u16)
    const int cx1 = ((4 | q) ^ r7) << 3;  // k-half 1
    const int aoff = (wm + r16) * 64;
    const int boff = 16384 + (wn + r16) * 64;

    f32x4 acc[8][4];
#pragma unroll
    for (int i = 0; i < 8; i++)
#pragma unroll
        for (int j = 0; j < 4; j++) acc[i][j] = (f32x4){0.f, 0.f, 0.f, 0.f};

    int tmc, tnc, tmn, tnn;
    const u16 *Ac, *Bc, *An, *Bn;
    bases_for(0, tmc, tnc, Ac, Bc);
    bases_for(1, tmn, tnn, An, Bn);

    // ---- prologue: buf0 <- tile0.kt0 (A,B), buf1.B <- tile0.kt1 (nt >= 2) ----
    stA(lds, 0, Ac, 0);
    stA(lds, 1, Ac, 0);
    stB(lds, 0, Bc, 0);
    stB(lds, 1, Bc, 0);
    stB(lds + 32768, 0, Bc, 1);
    stB(lds + 32768, 1, Bc, 1);

    for (int t = 0; t < tpb; ++t) {
        for (int it = 0; it < nt; ++it) {
            u16* sb = lds + ((it & 1) << 15);          // current buffer (nt even)
            u16* so = lds + (((it & 1) ^ 1) << 15);    // other buffer

            asm volatile("s_waitcnt vmcnt(4)" ::: "memory");
            __builtin_amdgcn_s_barrier();

            f16x8 vb[4][2];
#pragma unroll
            for (int ni = 0; ni < 4; ni++) {
                vb[ni][0] = *(const f16x8*)(sb + boff + ni * 1024 + cx0);
                vb[ni][1] = *(const f16x8*)(sb + boff + ni * 1024 + cx1);
            }

#pragma unroll
            for (int p = 0; p < 4; ++p) {
                f16x8 pa[2][2];
#pragma unroll
                for (int m2 = 0; m2 < 2; m2++) {
                    pa[m2][0] = *(const f16x8*)(sb + aoff + (2 * p + m2) * 1024 + cx0);
                    pa[m2][1] = *(const f16x8*)(sb + aoff + (2 * p + m2) * 1024 + cx1);
                }
                // staging: A one K-step ahead, B two ahead; tail redirects to next tile
                if (p == 0) {
                    if (it + 1 < nt) stA(so, 0, Ac, it + 1);
                    else             stA(so, 0, An, 0);
                } else if (p == 1) {
                    if (it + 1 < nt) stA(so, 1, Ac, it + 1);
                    else             stA(so, 1, An, 0);
                } else if (p == 2) {
                    if (it + 2 < nt) stB(sb, 0, Bc, it + 2);
                    else             stB(sb, 0, Bn, it + 2 - nt);
                } else {
                    if (it + 2 < nt) stB(sb, 1, Bc, it + 2);
                    else             stB(sb, 1, Bn, it + 2 - nt);
                }
                __builtin_amdgcn_s_barrier();
                asm volatile("s_waitcnt lgkmcnt(0)" ::: "memory");
                __builtin_amdgcn_s_setprio(1);
#pragma unroll
                for (int m2 = 0; m2 < 2; m2++)
#pragma unroll
                    for (int ni = 0; ni < 4; ni++) {
                        acc[2 * p + m2][ni] = __builtin_amdgcn_mfma_f32_16x16x32_f16(
                            pa[m2][0], vb[ni][0], acc[2 * p + m2][ni], 0, 0, 0);
                        acc[2 * p + m2][ni] = __builtin_amdgcn_mfma_f32_16x16x32_f16(
                            pa[m2][1], vb[ni][1], acc[2 * p + m2][ni], 0, 0, 0);
                    }
                __builtin_amdgcn_s_setprio(0);
                __builtin_amdgcn_s_barrier();
            }
        }

        // ---- epilogue for tile t (stores drain under the next tile's vmcnt) ----
#pragma unroll
        for (int mi = 0; mi < 8; mi++) {
#pragma unroll
            for (int ni = 0; ni < 4; ni++) {
                const int gcol = tnc + wn + ni * 16 + r16;
                float bv = 0.f;
                if (EPI) bv = bias[gcol];
#pragma unroll
                for (int j = 0; j < 4; j++) {
                    const int grow = tmc + wm + mi * 16 + q * 4 + j;
                    float v = acc[mi][ni][j];
                    if (EPI) v += bv;
                    if (EPI == 1) {
                        float tt = tanhf(0.7978845608028654f * (v + 0.044715f * v * v * v));
                        v = 0.5f * v * (1.0f + tt);
                    }
                    C[(long)grow * ldc + gcol] = f2h(v);
                    acc[mi][ni][j] = 0.f;
                }
            }
        }
        tmc = tmn; tnc = tnn; Ac = An; Bc = Bn;
        bases_for(t + 2, tmn, tnn, An, Bn);
    }

    asm volatile("s_waitcnt vmcnt(0)" ::: "memory");
}

// ================== 256x128 8-phase GEMM variant (narrow-N: Wo, FFN2) ==================
// BM=256, BN=128, BK=64, 512 threads = 8 waves (4M x 2N), per-wave output 64x64.
// Grid = (M/256)*(N/128) = 256 blocks -> exactly one generation (1 block/CU).
// LDS 96 KiB: 2 dbuf x (A[256][64]=32KB + B[128][64]=16KB); same XOR-chunk swizzle.
// 2 phases/K-tile x 16 MFMA; vmcnt(2) once per K-tile (in-flight [B:2, A:4, B':2]).
template <int EPI>
__global__ __launch_bounds__(512, 2) void gemm8p_n128(const u16* __restrict__ A,
                                                      const u16* __restrict__ BT,
                                                      u16* __restrict__ C,
                                                      const float* __restrict__ bias,
                                                      int M, int N, int K,
                                                      int lda, int ldc) {
    extern __shared__ u16 lds[];  // buf: A 16384 | B 8192 u16; buf stride 24576
    const int tid = threadIdx.x;

    const int ntn = N >> 7;
    int bid = blockIdx.x;
    {
        const int cpx = gridDim.x >> 3;
        bid = (bid & 7) * cpx + (bid >> 3);
    }
    const int tm = (bid / ntn) << 8;
    const int tn = (bid % ntn) << 7;

    const int srow = tid >> 3;
    const int scol = ((tid & 7) ^ (srow & 7)) << 3;
    const u16* Abase = A + (long)(tm + srow) * lda + scol;
    const u16* Bbase = BT + (long)(tn + srow) * (long)K + scol;
    const long lda64 = (long)lda << 6;
    const long ldb64 = (long)K << 6;

    const int nt = K >> 6;

    auto stA = [&](u16* bufbase, int h, int kt) {
        u16* d = bufbase + h * 8192 + tid * 8;
        const u16* g = Abase + (long)(h * 128) * lda + (kt << 6);
        gload_lds16(g, d);
        gload_lds16(g + lda64, d + 4096);
    };
    auto stB = [&](u16* bufbase, int kt) {
        u16* d = bufbase + 16384 + tid * 8;
        const u16* g = Bbase + (kt << 6);
        gload_lds16(g, d);
        gload_lds16(g + ldb64, d + 4096);
    };

    const int wid = tid >> 6, lane = tid & 63;
    const int r16 = lane & 15, q = lane >> 4;
    const int wm = (wid >> 1) * 64;      // 0 / 64 / 128 / 192
    const int wn = (wid & 1) * 64;       // 0 / 64
    const int r7 = r16 & 7;
    const int cx0 = (q ^ r7) << 3;
    const int cx1 = ((4 | q) ^ r7) << 3;
    const int aoff = (wm + r16) * 64;
    const int boff = 16384 + (wn + r16) * 64;

    f32x4 acc[4][4];
#pragma unroll
    for (int i = 0; i < 4; i++)
#pragma unroll
        for (int j = 0; j < 4; j++) acc[i][j] = (f32x4){0.f, 0.f, 0.f, 0.f};

    // prologue: buf0 <- tile0 (A,B); buf1.B <- tile1
    {
        const int t1 = nt > 1 ? 1 : 0;
        stA(lds, 0, 0);
        stA(lds, 1, 0);
        stB(lds, 0);
        stB(lds + 24576, t1);
    }

    for (int it = 0; it < nt; ++it) {
        u16* sb = lds + (it & 1) * 24576;
        u16* so = lds + ((it & 1) ^ 1) * 24576;
        const int tA = (it + 1 < nt) ? it + 1 : nt - 1;
        const int tB = (it + 2 < nt) ? it + 2 : nt - 1;

        asm volatile("s_waitcnt vmcnt(2)" ::: "memory");
        __builtin_amdgcn_s_barrier();

        f16x8 vb[4][2];
#pragma unroll
        for (int ni = 0; ni < 4; ni++) {
            vb[ni][0] = *(const f16x8*)(sb + boff + ni * 1024 + cx0);
            vb[ni][1] = *(const f16x8*)(sb + boff + ni * 1024 + cx1);
        }

#pragma unroll
        for (int p = 0; p < 2; ++p) {
            f16x8 pa[2][2];
#pragma unroll
            for (int m2 = 0; m2 < 2; m2++) {
                pa[m2][0] = *(const f16x8*)(sb + aoff + (2 * p + m2) * 1024 + cx0);
                pa[m2][1] = *(const f16x8*)(sb + aoff + (2 * p + m2) * 1024 + cx1);
            }
            if (p == 0) {
                stA(so, 0, tA);
            } else {
                stA(so, 1, tA);
                stB(sb, tB);
            }
            __builtin_amdgcn_s_barrier();
            asm volatile("s_waitcnt lgkmcnt(0)" ::: "memory");
            __builtin_amdgcn_s_setprio(1);
#pragma unroll
            for (int m2 = 0; m2 < 2; m2++)
#pragma unroll
                for (int ni = 0; ni < 4; ni++) {
                    acc[2 * p + m2][ni] = __builtin_amdgcn_mfma_f32_16x16x32_f16(
                        pa[m2][0], vb[ni][0], acc[2 * p + m2][ni], 0, 0, 0);
                    acc[2 * p + m2][ni] = __builtin_amdgcn_mfma_f32_16x16x32_f16(
                        pa[m2][1], vb[ni][1], acc[2 * p + m2][ni], 0, 0, 0);
                }
            __builtin_amdgcn_s_setprio(0);
            __builtin_amdgcn_s_barrier();
        }
    }

    asm volatile("s_waitcnt vmcnt(0)" ::: "memory");

#pragma unroll
    for (int mi = 0; mi < 4; mi++) {
#pragma unroll
        for (int ni = 0; ni < 4; ni++) {
            const int gcol = tn + wn + ni * 16 + r16;
            float bv = 0.f;
            if (EPI) bv = bias[gcol];
#pragma unroll
            for (int j = 0; j < 4; j++) {
                const int grow = tm + wm + mi * 16 + q * 4 + j;
                float v = acc[mi][ni][j];
                if (EPI) v += bv;
                if (EPI == 1) {
                    float t = tanhf(0.7978845608028654f * (v + 0.044715f * v * v * v));
                    v = 0.5f * v * (1.0f + t);
                }
                C[(long)grow * ldc + gcol] = f2h(v);
            }
        }
    }
}

// ---------------- a_c transform helper ----------------
__device__ __forceinline__ void a_transform(float ar, float ai, float& cr, float& ci) {
    float m = sqrtf(ar * ar + ai * ai);
    float sg = 1.f / (1.f + __expf(-m));
    float sc = sg / fmaxf(m, 1e-30f);
    cr = ar * sc;
    ci = ai * sc;
}

// pcat column offsets: Q=0, K=1024, V=2048, AR=3072, AI=4096, G=5120; row stride PW.
// ---------------- scan phase 1: per-chunk reduce ----------------
__global__ __launch_bounds__(1024) void scan1(const u16* __restrict__ pcat,
                                              float4* __restrict__ sum4) {
    const int b = blockIdx.y, c = blockIdx.x, d = threadIdx.x;
    float Arp = 1.f, Aip = 0.f, Xr = 0.f, Xi = 0.f;
    const long rowbase = (long)b * Ss + (long)c * TCH;
#pragma unroll 4
    for (int s = 0; s < TCH; ++s) {
        const long ro = (rowbase + s) * PW;
        float ar = h2f(pcat[ro + 3072 + d]);
        float ai = h2f(pcat[ro + 4096 + d]);
        float kk = h2f(pcat[ro + 1024 + d]);
        float vv = h2f(pcat[ro + 2048 + d]);
        float cr, ci;
        a_transform(ar, ai, cr, ci);
        float kv = kk * vv;
        float nXr = cr * Xr - ci * Xi + kv;
        float nXi = cr * Xi + ci * Xr;
        Xr = nXr; Xi = nXi;
        float nAr = cr * Arp - ci * Aip;
        float nAi = cr * Aip + ci * Arp;
        Arp = nAr; Aip = nAi;
    }
    sum4[((long)b * NCH + c) * 1024 + d] = make_float4(Arp, Aip, Xr, Xi);
}

// ---------------- scan phase 2: sequential carry across chunks ----------------
__global__ __launch_bounds__(256) void scan2(const float4* __restrict__ sum4,
                                             float2* __restrict__ carry) {
    const int idx = blockIdx.x * 256 + threadIdx.x;  // 0..2047
    const int b = idx >> 10, d = idx & 1023;
    float hr = 0.f, hi = 0.f;
    for (int cb = 0; cb < NCH / 8; ++cb) {
        float4 t[8];
#pragma unroll
        for (int j = 0; j < 8; j++)
            t[j] = sum4[((long)b * NCH + cb * 8 + j) * 1024 + d];
#pragma unroll
        for (int j = 0; j < 8; j++) {
            carry[((long)b * NCH + cb * 8 + j) * 1024 + d] = make_float2(hr, hi);
            float nr = t[j].x * hr - t[j].y * hi + t[j].z;
            float ni = t[j].x * hi + t[j].y * hr + t[j].w;
            hr = nr; hi = ni;
        }
    }
}

// -------- scan phase 3: re-scan with carry, fused silu/q gating; y over Q in-place --------
__global__ __launch_bounds__(1024) void scan3(u16* pcat,
                                              const float2* __restrict__ carry) {
    const int b = blockIdx.y, c = blockIdx.x, d = threadIdx.x;
    float2 h0 = carry[((long)b * NCH + c) * 1024 + d];
    float hr = h0.x, hi = h0.y;
    const long rowbase = (long)b * Ss + (long)c * TCH;
#pragma unroll 4
    for (int s = 0; s < TCH; ++s) {
        const long ro = (rowbase + s) * PW;
        float ar = h2f(pcat[ro + 3072 + d]);
        float ai = h2f(pcat[ro + 4096 + d]);
        float kk = h2f(pcat[ro + 1024 + d]);
        float vv = h2f(pcat[ro + 2048 + d]);
        float cr, ci;
        a_transform(ar, ai, cr, ci);
        float kv = kk * vv;
        float nhr = cr * hr - ci * hi + kv;
        float nhi = cr * hi + ci * hr;
        hr = nhr; hi = nhi;
        float gg = h2f(pcat[ro + 5120 + d]);
        float si = gg / (1.f + __expf(-gg));
        float yv = h2f(pcat[ro + d]) * hr * si;
        pcat[ro + d] = f2h(yv);
    }
}

// ---------------- layernorm: out = LN(a + res) * scale + bias ----------------
// a: fp16 (stride sa). RESF32: res fp32 (stride sres). OUTF32: out fp32 (stride sout).
template <int RESF32, int OUTF32>
__global__ __launch_bounds__(256) void ln_kernel(const u16* __restrict__ a, int sa,
                                                 const void* __restrict__ bres, int sres,
                                                 const float* __restrict__ scale,
                                                 const float* __restrict__ bias,
                                                 void* __restrict__ out, int sout) {
    const int row = blockIdx.x;
    const int tid = threadIdx.x;
    const long abase = (long)row * sa;
    const long rbase = (long)row * sres;
    const long obase = (long)row * sout;
    float v[4];
#pragma unroll
    for (int j = 0; j < 4; j++) {
        int d = tid * 4 + j;
        float rb = RESF32 ? ((const float*)bres)[rbase + d]
                          : h2f(((const u16*)bres)[rbase + d]);
        v[j] = h2f(a[abase + d]) + rb;
    }
    float s = v[0] + v[1] + v[2] + v[3];
    float s2 = v[0] * v[0] + v[1] * v[1] + v[2] * v[2] + v[3] * v[3];
#pragma unroll
    for (int off = 32; off; off >>= 1) {
        s += __shfl_down(s, off);
        s2 += __shfl_down(s2, off);
    }
    __shared__ float red[8];
    const int w = tid >> 6, lane = tid & 63;
    if (lane == 0) { red[w] = s; red[4 + w] = s2; }
    __syncthreads();
    if (tid == 0) {
        float ts = red[0] + red[1] + red[2] + red[3];
        float ts2 = red[4] + red[5] + red[6] + red[7];
        float mu = ts * (1.f / 1024.f);
        float var = ts2 * (1.f / 1024.f) - mu * mu;
        red[0] = mu;
        red[1] = rsqrtf(var + 1e-6f);
    }
    __syncthreads();
    const float mu = red[0], rs = red[1];
#pragma unroll
    for (int j = 0; j < 4; j++) {
        int d = tid * 4 + j;
        float y = (v[j] - mu) * rs * scale[d] + bias[d];
        if (OUTF32) ((float*)out)[obase + d] = y;
        else        ((u16*)out)[obase + d] = f2h(y);
    }
}

extern "C" void kernel_launch(void* const* d_in, const int* in_sizes, int n_in,
                              void* d_out, int out_size, void* d_ws, size_t ws_size,
                              hipStream_t stream) {
    const float* x    = (const float*)d_in[0];
    const float* Wq   = (const float*)d_in[1];
    const float* Wk   = (const float*)d_in[2];
    const float* Wv   = (const float*)d_in[3];
    const float* Wa   = (const float*)d_in[4];
    const float* Wg   = (const float*)d_in[5];
    const float* Wo   = (const float*)d_in[6];
    const float* ln1s = (const float*)d_in[7];
    const float* ln1b = (const float*)d_in[8];
    const float* W1   = (const float*)d_in[9];
    const float* b1   = (const float*)d_in[10];
    const float* W2   = (const float*)d_in[11];
    const float* b2   = (const float*)d_in[12];
    const float* ln2s = (const float*)d_in[13];
    const float* ln2b = (const float*)d_in[14];

    // ---- workspace layout (u16 elements), 142 MiB total ----
    u16* ws    = (u16*)d_ws;
    u16* xb    = ws;                        // 8M   x as fp16
    u16* WTcat = xb + (8u << 20);           // 6M   [6144,1024] fused proj weights^T
    u16* WTo   = WTcat + (6u << 20);        // 1M
    u16* WT1   = WTo + (1u << 20);          // 4M
    u16* WT2   = WT1 + (4u << 20);          // 4M
    u16* pcat  = WT2 + (4u << 20);          // 48M  [8192,6144] everything lives here
    // total = 71M u16 = 142 MiB

    // scan scratch overlays WTcat (dead after the fused projection GEMM)
    float4* sum4  = (float4*)WTcat;               // 4 MiB
    float2* carry = (float2*)(WTcat + (2u << 20)); // 2 MiB @ +4 MiB

    // allow big dynamic LDS for the 8-phase GEMMs (once; host-side, capture-safe)
    static bool attr_done = false;
    if (!attr_done) {
        hipFuncSetAttribute(reinterpret_cast<const void*>(&gemm8p<0>),
                            hipFuncAttributeMaxDynamicSharedMemorySize, 131072);
        hipFuncSetAttribute(reinterpret_cast<const void*>(&gemm8p<1>),
                            hipFuncAttributeMaxDynamicSharedMemorySize, 131072);
        hipFuncSetAttribute(reinterpret_cast<const void*>(&gemm8p_n128<0>),
                            hipFuncAttributeMaxDynamicSharedMemorySize, 98304);
        hipFuncSetAttribute(reinterpret_cast<const void*>(&gemm8p_n128<2>),
                            hipFuncAttributeMaxDynamicSharedMemorySize, 98304);
        attr_done = true;
    }

    // pcat column slices (row stride PW=6144):
    //   Q=+0  K=+1024  V=+2048  AR=+3072  AI=+4096  G=+5120
    // liveness ladder: scan3 writes y over Q; Wo-GEMM Q->K(o1); LN1 K->Q(yln);
    // FFN1 Q->cols[2048,6144)(hmat); FFN2 hmat->K(o2); LN2 (K,Q)->d_out.

    // fused prep: x->fp16 + all weight transposes (one launch)
    prep_fused<<<dim3(23552), dim3(256), 0, stream>>>(x, xb, Wq, Wk, Wv, Wa, Wg, Wo,
                                                      W1, W2, WTcat, WTo, WT1, WT2);

    // fused q|k|v|a|g projection: [8192,1024] @ [1024,6144] -> pcat
    // persistent 256 blocks x 3 tiles (768 total)
    gemm8p<0><<<dim3(256), dim3(512), 131072, stream>>>(xb, WTcat, pcat, nullptr,
                                                        Mtok, PW, 1024, 1024, PW);
    // gate-loop scan
    scan1<<<dim3(NCH, Bb), 1024, 0, stream>>>(pcat, sum4);
    scan2<<<dim3(8), 256, 0, stream>>>(sum4, carry);
    scan3<<<dim3(NCH, Bb), 1024, 0, stream>>>(pcat, carry);
    // output proj: y(Q slice) @ Wo -> o1(K slice)   (256x128 8-phase, 256 blocks)
    gemm8p_n128<0><<<dim3(256), dim3(512), 98304, stream>>>(pcat, WTo, pcat + 1024,
                                                            nullptr,
                                                            Mtok, 1024, 1024, PW, PW);
    // LN1: o1 + x -> yln(Q slice)
    ln_kernel<1, 0><<<dim3(Mtok), dim3(256), 0, stream>>>(pcat + 1024, PW, x, 1024,
                                                          ln1s, ln1b, pcat, PW);
    // FFN1: yln @ W1 + b1, gelu -> hmat(cols 2048..6144)
    // persistent 256 blocks x 2 tiles (512 total)
    gemm8p<1><<<dim3(256), dim3(512), 131072, stream>>>(pcat, WT1, pcat + 2048, b1,
                                                        Mtok, Ff, 1024, PW, PW);
    // FFN2: hmat @ W2 + b2 -> o2(K slice)   (256x128 8-phase, 256 blocks, 64 K-tiles)
    gemm8p_n128<2><<<dim3(256), dim3(512), 98304, stream>>>(pcat + 2048, WT2,
                                                            pcat + 1024, b2,
                                                            Mtok, 1024, Ff, PW, PW);
    // LN2: o2 + yln -> fp32 d_out
    ln_kernel<0, 1><<<dim3(Mtok), dim3(256), 0, stream>>>(pcat + 1024, PW, pcat, PW,
                                                          ln2s, ln2b, d_out, 1024);
}